// Round 1
// baseline (260.035 us; speedup 1.0000x reference)
//
#include <hip/hip_runtime.h>

typedef unsigned short u16;
typedef __attribute__((ext_vector_type(8))) short short8v;
typedef __attribute__((ext_vector_type(4))) float floatx4;

#define B_ 16
#define C_ 512
#define N_ 4096
#define K_ 128   // keys
#define NT 64    // pixels per block

__device__ __forceinline__ float bf2f(u16 u) {
    unsigned int x = ((unsigned int)u) << 16;
    return __builtin_bit_cast(float, x);
}
__device__ __forceinline__ u16 f2bf(float f) {
    unsigned int u = __builtin_bit_cast(unsigned int, f);
    u = u + 0x7FFFu + ((u >> 16) & 1u);
    return (u16)(u >> 16);
}

// ---------------------------------------------------------------------------
// P0: fp32 -> bf16 converts (y1,y2,wk1,wk2,wv1,wv2), one launch
// ---------------------------------------------------------------------------
__global__ void conv_all(const float* __restrict__ y1, const float* __restrict__ y2,
                         const float* __restrict__ wk1, const float* __restrict__ wk2,
                         const float* __restrict__ wv1, const float* __restrict__ wv2,
                         u16* y1b, u16* y2b, u16* wk1b, u16* wk2b, u16* wv1b, u16* wv2b) {
    int tid = blockIdx.x * 256 + threadIdx.x;
    const int SY = B_ * K_ * C_;        // 1048576
    const int SWK = 256 * 512;          // 131072
    const int SWV = 512 * 512;          // 262144
    const float* src; u16* dst; int off;
    if (tid < SY)                 { src = y1;  dst = y1b;  off = tid; }
    else if (tid < 2*SY)          { src = y2;  dst = y2b;  off = tid - SY; }
    else if (tid < 2*SY+SWK)      { src = wk1; dst = wk1b; off = tid - 2*SY; }
    else if (tid < 2*SY+2*SWK)    { src = wk2; dst = wk2b; off = tid - 2*SY - SWK; }
    else if (tid < 2*SY+2*SWK+SWV){ src = wv1; dst = wv1b; off = tid - 2*SY - 2*SWK; }
    else                          { src = wv2; dst = wv2b; off = tid - 2*SY - 2*SWK - SWV; }
    dst[off] = f2bf(src[off]);
}

// P0b: wq transpose+convert: wqXt[c][d] = wqX[d][c]
__global__ void conv_wqt(const float* __restrict__ wq1, const float* __restrict__ wq2,
                         u16* wq1t, u16* wq2t) {
    int tid = blockIdx.x * 256 + threadIdx.x;          // 131072 total
    const float* s = (tid & 65536) ? wq2 : wq1;
    u16* d = (tid & 65536) ? wq2t : wq1t;
    int e = tid & 65535;
    int dd = e >> 9;          // 0..127
    int c = e & 511;          // coalesced read over c
    d[c * 128 + dd] = f2bf(s[dd * 512 + c]);
}

// ---------------------------------------------------------------------------
// P1: k1b/k2b [b][key][256] bf16 = y @ wk^T + bk
// grid (2, 4, 32) block 64
// ---------------------------------------------------------------------------
__global__ void gemm_gk(const u16* __restrict__ y1b, const u16* __restrict__ y2b,
                        const u16* __restrict__ wk1b, const u16* __restrict__ wk2b,
                        const float* __restrict__ bk1, const float* __restrict__ bk2,
                        u16* k1b, u16* k2b) {
    int l = threadIdx.x;
    int z = blockIdx.z; int b = z >> 1; int which = z & 1;
    const u16* A = (which ? y2b : y1b) + (size_t)b * K_ * C_;
    const u16* Wt = which ? wk2b : wk1b;
    const float* bias = which ? bk2 : bk1;
    u16* outp = (which ? k2b : k1b) + (size_t)b * K_ * 256;
    int m0 = blockIdx.x * 64, n0 = blockIdx.y * 64;
    floatx4 acc[4][4] = {};
    for (int ch = 0; ch < 16; ++ch) {
        int koff = ch * 32 + (l >> 4) * 8;
        short8v a[4], wv[4];
#pragma unroll
        for (int mf = 0; mf < 4; ++mf) a[mf] = *(const short8v*)(A + (size_t)(m0 + mf*16 + (l & 15)) * 512 + koff);
#pragma unroll
        for (int nf = 0; nf < 4; ++nf) wv[nf] = *(const short8v*)(Wt + (size_t)(n0 + nf*16 + (l & 15)) * 512 + koff);
#pragma unroll
        for (int mf = 0; mf < 4; ++mf)
#pragma unroll
            for (int nf = 0; nf < 4; ++nf)
                acc[mf][nf] = __builtin_amdgcn_mfma_f32_16x16x32_bf16(a[mf], wv[nf], acc[mf][nf], 0, 0, 0);
    }
#pragma unroll
    for (int mf = 0; mf < 4; ++mf)
#pragma unroll
        for (int nf = 0; nf < 4; ++nf)
#pragma unroll
            for (int rg = 0; rg < 4; ++rg) {
                int m = m0 + mf*16 + (l >> 4)*4 + rg;
                int n = n0 + nf*16 + (l & 15);
                outp[(size_t)m * 256 + n] = f2bf(acc[mf][nf][rg] + bias[n]);
            }
}

// ---------------------------------------------------------------------------
// P2: ebias1/2[b][key] = bq_cat . k_row
// ---------------------------------------------------------------------------
__global__ void ebias_k(const u16* __restrict__ k1b, const u16* __restrict__ k2b,
                        const float* __restrict__ bq1, const float* __restrict__ bq2,
                        float* eb1, float* eb2) {
    int tid = blockIdx.x * 256 + threadIdx.x;  // 4096
    int pair = tid >> 11; int inner = tid & 2047;
    int b = inner >> 7; int key = inner & 127;
    const u16* kb = (pair ? k2b : k1b) + ((size_t)(b * 128 + key)) * 256;
    float s = 0.f;
    for (int d = 0; d < 128; ++d) s += bq1[d] * bf2f(kb[d]);
    for (int d = 0; d < 128; ++d) s += bq2[d] * bf2f(kb[128 + d]);
    (pair ? eb2 : eb1)[b * 128 + key] = s;
}

// ---------------------------------------------------------------------------
// P3: kk** [b][key][512] bf16: kk = k_half @ wqt^T(over d)
// grid (2, 8, 64) block 64    z = b*4 + which(0:kk11 1:kk12 2:kk21 3:kk22)
// ---------------------------------------------------------------------------
__global__ void gemm_gkk(const u16* __restrict__ k1b, const u16* __restrict__ k2b,
                         const u16* __restrict__ wq1t, const u16* __restrict__ wq2t,
                         u16* kk11, u16* kk12, u16* kk21, u16* kk22) {
    int l = threadIdx.x;
    int z = blockIdx.z; int b = z >> 2; int which = z & 3;
    const u16* A = ((which < 2) ? k1b : k2b) + (size_t)b * K_ * 256 + (which & 1) * 128;
    const u16* Wt = (which & 1) ? wq2t : wq1t;
    u16* outp;
    switch (which) { case 0: outp = kk11; break; case 1: outp = kk12; break;
                     case 2: outp = kk21; break; default: outp = kk22; }
    outp += (size_t)b * K_ * C_;
    int m0 = blockIdx.x * 64, n0 = blockIdx.y * 64;
    floatx4 acc[4][4] = {};
    for (int ch = 0; ch < 4; ++ch) {
        int koff = ch * 32 + (l >> 4) * 8;
        short8v a[4], wv[4];
#pragma unroll
        for (int mf = 0; mf < 4; ++mf) a[mf] = *(const short8v*)(A + (size_t)(m0 + mf*16 + (l & 15)) * 256 + koff);
#pragma unroll
        for (int nf = 0; nf < 4; ++nf) wv[nf] = *(const short8v*)(Wt + (size_t)(n0 + nf*16 + (l & 15)) * 128 + koff);
#pragma unroll
        for (int mf = 0; mf < 4; ++mf)
#pragma unroll
            for (int nf = 0; nf < 4; ++nf)
                acc[mf][nf] = __builtin_amdgcn_mfma_f32_16x16x32_bf16(a[mf], wv[nf], acc[mf][nf], 0, 0, 0);
    }
#pragma unroll
    for (int mf = 0; mf < 4; ++mf)
#pragma unroll
        for (int nf = 0; nf < 4; ++nf)
#pragma unroll
            for (int rg = 0; rg < 4; ++rg) {
                int m = m0 + mf*16 + (l >> 4)*4 + rg;
                int n = n0 + nf*16 + (l & 15);
                outp[(size_t)m * C_ + n] = f2bf(acc[mf][nf][rg]);
            }
}

// ---------------------------------------------------------------------------
// P4: vt1/vt2 [b][c][128] bf16 = (y @ wv^T + bv) transposed
// grid (8, 2, 32) block 64
// ---------------------------------------------------------------------------
__global__ void gemm_gv(const u16* __restrict__ wv1b, const u16* __restrict__ wv2b,
                        const u16* __restrict__ y1b, const u16* __restrict__ y2b,
                        const float* __restrict__ bv1, const float* __restrict__ bv2,
                        u16* vt1, u16* vt2) {
    int l = threadIdx.x;
    int z = blockIdx.z; int b = z >> 1; int which = z & 1;
    const u16* A = which ? wv2b : wv1b;                              // [512][512]
    const u16* Wt = (which ? y2b : y1b) + (size_t)b * K_ * C_;       // [128][512]
    const float* bias = which ? bv2 : bv1;
    u16* outp = (which ? vt2 : vt1) + (size_t)b * C_ * K_;
    int m0 = blockIdx.x * 64, n0 = blockIdx.y * 64;
    floatx4 acc[4][4] = {};
    for (int ch = 0; ch < 16; ++ch) {
        int koff = ch * 32 + (l >> 4) * 8;
        short8v a[4], wv[4];
#pragma unroll
        for (int mf = 0; mf < 4; ++mf) a[mf] = *(const short8v*)(A + (size_t)(m0 + mf*16 + (l & 15)) * 512 + koff);
#pragma unroll
        for (int nf = 0; nf < 4; ++nf) wv[nf] = *(const short8v*)(Wt + (size_t)(n0 + nf*16 + (l & 15)) * 512 + koff);
#pragma unroll
        for (int mf = 0; mf < 4; ++mf)
#pragma unroll
            for (int nf = 0; nf < 4; ++nf)
                acc[mf][nf] = __builtin_amdgcn_mfma_f32_16x16x32_bf16(a[mf], wv[nf], acc[mf][nf], 0, 0, 0);
    }
#pragma unroll
    for (int mf = 0; mf < 4; ++mf)
#pragma unroll
        for (int nf = 0; nf < 4; ++nf)
#pragma unroll
            for (int rg = 0; rg < 4; ++rg) {
                int m = m0 + mf*16 + (l >> 4)*4 + rg;
                int n = n0 + nf*16 + (l & 15);
                outp[(size_t)m * K_ + n] = f2bf(acc[mf][nf][rg] + bias[m]);
            }
}

// ---------------------------------------------------------------------------
// Main fused kernel: E = x.kk (K=1024), softmax(|e1-e2|), O = vt.attn^T, residual
// grid 1024, block 256 (4 waves)
// ---------------------------------------------------------------------------
__global__ __launch_bounds__(256, 2)
void main_attn(const float* __restrict__ x1, const float* __restrict__ x2,
               const u16* __restrict__ kk11, const u16* __restrict__ kk12,
               const u16* __restrict__ kk21, const u16* __restrict__ kk22,
               const u16* __restrict__ vt1, const u16* __restrict__ vt2,
               const float* __restrict__ eb1, const float* __restrict__ eb2,
               const float* __restrict__ scale_p,
               float* __restrict__ out1, float* __restrict__ out2) {
    __shared__ u16 regionA[20480];        // 40960 B: xT[64][64] + kk1s[128][64] + kk2s[128][64]
    __shared__ u16 attn_s[64 * 128];      // 16384 B, swizzled bf16 attn

    u16* xT = regionA;                    // pitch 64 shorts (128B), 8 granules/row
    u16* kk1s = regionA + 4096;
    u16* kk2s = regionA + 4096 + 8192;
    float* s_f = (float*)regionA;         // [64][132]
    float* red1 = (float*)regionA + 64 * 132;  // [4][64]
    float* red2 = red1 + 256;

    int bid0 = blockIdx.x;
    int bid = ((bid0 & 7) << 7) | (bid0 >> 3);   // XCD swizzle (1024 = 8*128, bijective)
    int b = bid >> 6;
    int n0 = (bid & 63) * NT;
    int t = threadIdx.x;
    int w = t >> 6;
    int l = t & 63;

    const float sc = scale_p[0];

    floatx4 e1a[4][2] = {}; floatx4 e2a[4][2] = {};

    const float* xs0 = x1 + (size_t)b * C_ * N_;
    const float* xs1 = x2 + (size_t)b * C_ * N_;
    const u16* kkAh[2] = { kk11 + (size_t)b * K_ * C_, kk12 + (size_t)b * K_ * C_ };
    const u16* kkBh[2] = { kk21 + (size_t)b * K_ * C_, kk22 + (size_t)b * K_ * C_ };

    for (int r = 0; r < 16; ++r) {
        int half = r >> 3;
        int c0 = (r & 7) * 64;
        // ---- stage xT (transpose + bf16): wave covers c-block w*16 + (l>>5)*8, n-pair 2*(l&31)
        {
            const float* xp = (half ? xs1 : xs0) + (size_t)(c0 + w * 16 + (l >> 5) * 8) * N_ + n0 + 2 * (l & 31);
            float v0[8], v1[8];
#pragma unroll
            for (int j = 0; j < 8; ++j) { float2 f = *(const float2*)(xp + (size_t)j * N_); v0[j] = f.x; v1[j] = f.y; }
            short8v p0, p1;
#pragma unroll
            for (int j = 0; j < 8; ++j) { p0[j] = (short)f2bf(v0[j]); p1[j] = (short)f2bf(v1[j]); }
            int row0 = 2 * (l & 31), row1 = row0 + 1;
            int g = w * 2 + (l >> 5);
            *(short8v*)&xT[row0 * 64 + 8 * (g ^ (row0 & 7))] = p0;
            *(short8v*)&xT[row1 * 64 + 8 * (g ^ (row1 & 7))] = p1;
        }
        // ---- stage kk1s/kk2s: lane: key = w*32 + (l>>1), 4 granules each
        {
            int key = w * 32 + (l >> 1);
            const u16* s1 = kkAh[half] + (size_t)key * C_ + c0;
            const u16* s2 = kkBh[half] + (size_t)key * C_ + c0;
#pragma unroll
            for (int i = 0; i < 4; ++i) {
                int g = (l & 1) * 4 + i;
                short8v q1 = *(const short8v*)(s1 + g * 8);
                short8v q2 = *(const short8v*)(s2 + g * 8);
                int didx = key * 64 + 8 * (g ^ (key & 7));
                *(short8v*)&kk1s[didx] = q1;
                *(short8v*)&kk2s[didx] = q2;
            }
        }
        __syncthreads();
        // ---- MFMA: E1/E2 [64n x 128key] over 64 channels (2 chunks of 32)
#pragma unroll
        for (int ch = 0; ch < 2; ++ch) {
            short8v a[4];
#pragma unroll
            for (int mf = 0; mf < 4; ++mf) {
                int row = mf * 16 + (l & 15);
                int g = ch * 4 + (l >> 4);
                a[mf] = *(const short8v*)&xT[row * 64 + 8 * (g ^ (row & 7))];
            }
#pragma unroll
            for (int kf = 0; kf < 2; ++kf) {
                int krow = w * 32 + kf * 16 + (l & 15);
                int g = ch * 4 + (l >> 4);
                int idx = krow * 64 + 8 * (g ^ (krow & 7));
                short8v b1 = *(const short8v*)&kk1s[idx];
                short8v b2 = *(const short8v*)&kk2s[idx];
#pragma unroll
                for (int mf = 0; mf < 4; ++mf) {
                    e1a[mf][kf] = __builtin_amdgcn_mfma_f32_16x16x32_bf16(a[mf], b1, e1a[mf][kf], 0, 0, 0);
                    e2a[mf][kf] = __builtin_amdgcn_mfma_f32_16x16x32_bf16(a[mf], b2, e2a[mf][kf], 0, 0, 0);
                }
            }
        }
        __syncthreads();
    }

    // ---- softmax over keys of |e1 - e2| (with folded q-bias terms)
    float ebv1[2], ebv2[2];
#pragma unroll
    for (int kf = 0; kf < 2; ++kf) {
        int kc = w * 32 + kf * 16 + (l & 15);
        ebv1[kf] = eb1[b * 128 + kc];
        ebv2[kf] = eb2[b * 128 + kc];
    }
#pragma unroll
    for (int mf = 0; mf < 4; ++mf)
#pragma unroll
        for (int kf = 0; kf < 2; ++kf)
#pragma unroll
            for (int rg = 0; rg < 4; ++rg) {
                int row = mf * 16 + (l >> 4) * 4 + rg;
                int col = w * 32 + kf * 16 + (l & 15);
                s_f[row * 132 + col] = fabsf(e1a[mf][kf][rg] + ebv1[kf] - e2a[mf][kf][rg] - ebv2[kf]);
            }
    __syncthreads();
    {
        int rrow = l; int q = w;
        float m = -1e30f;
        for (int i = 0; i < 32; ++i) m = fmaxf(m, s_f[rrow * 132 + q * 32 + i]);
        red1[q * 64 + rrow] = m;
        __syncthreads();
        float mrow = fmaxf(fmaxf(red1[rrow], red1[64 + rrow]), fmaxf(red1[128 + rrow], red1[192 + rrow]));
        float ps = 0.f;
        for (int i = 0; i < 32; ++i) {
            float e = __expf(s_f[rrow * 132 + q * 32 + i] - mrow);
            s_f[rrow * 132 + q * 32 + i] = e;
            ps += e;
        }
        red2[q * 64 + rrow] = ps;
        __syncthreads();
        float inv = 1.0f / (red2[rrow] + red2[64 + rrow] + red2[128 + rrow] + red2[192 + rrow]);
#pragma unroll
        for (int g2 = 0; g2 < 4; ++g2) {
            int g = q * 4 + g2;
            short8v pk;
#pragma unroll
            for (int j = 0; j < 8; ++j) pk[j] = (short)f2bf(s_f[rrow * 132 + g * 8 + j] * inv);
            *(short8v*)&attn_s[rrow * 128 + 8 * (g ^ (rrow & 7))] = pk;
        }
    }
    __syncthreads();

    // ---- PV: O[c][n] = vt[c][k] . attn[n][k], + residual
    for (int oi = 0; oi < 2; ++oi) {
        const u16* vt = (oi ? vt2 : vt1) + (size_t)b * C_ * K_;
        const float* xr = oi ? xs1 : xs0;
        float* op = (oi ? out2 : out1) + (size_t)b * C_ * N_;
        for (int cc = 0; cc < 4; ++cc) {
            {   // stage vts[128][128] bf16 swizzled
                int rowl = t >> 1;
                const u16* vs = vt + (size_t)(cc * 128 + rowl) * K_;
#pragma unroll
                for (int i = 0; i < 8; ++i) {
                    int g = (t & 1) * 8 + i;
                    short8v q0 = *(const short8v*)(vs + g * 8);
                    *(short8v*)&regionA[rowl * 128 + 8 * (g ^ (rowl & 7))] = q0;
                }
            }
            __syncthreads();
            floatx4 o[2][4] = {};
#pragma unroll
            for (int kc = 0; kc < 4; ++kc) {
                short8v a[2];
#pragma unroll
                for (int mf = 0; mf < 2; ++mf) {
                    int row = w * 32 + mf * 16 + (l & 15);
                    int g = kc * 4 + (l >> 4);
                    a[mf] = *(const short8v*)&regionA[row * 128 + 8 * (g ^ (row & 7))];
                }
#pragma unroll
                for (int nf = 0; nf < 4; ++nf) {
                    int nrow = nf * 16 + (l & 15);
                    int g = kc * 4 + (l >> 4);
                    short8v bb = *(const short8v*)&attn_s[nrow * 128 + 8 * (g ^ (nrow & 7))];
#pragma unroll
                    for (int mf = 0; mf < 2; ++mf)
                        o[mf][nf] = __builtin_amdgcn_mfma_f32_16x16x32_bf16(a[mf], bb, o[mf][nf], 0, 0, 0);
                }
            }
#pragma unroll
            for (int mf = 0; mf < 2; ++mf)
#pragma unroll
                for (int nf = 0; nf < 4; ++nf)
#pragma unroll
                    for (int rg = 0; rg < 4; ++rg) {
                        int c = cc * 128 + w * 32 + mf * 16 + (l >> 4) * 4 + rg;
                        int n = n0 + nf * 16 + (l & 15);
                        size_t idx = (size_t)c * N_ + n;
                        op[idx] = sc * o[mf][nf][rg] + xr[idx];
                    }
            __syncthreads();
        }
    }
}

// ---------------------------------------------------------------------------
extern "C" void kernel_launch(void* const* d_in, const int* in_sizes, int n_in,
                              void* d_out, int out_size, void* d_ws, size_t ws_size,
                              hipStream_t stream) {
    const float* x1 = (const float*)d_in[0];
    const float* y1 = (const float*)d_in[1];
    const float* x2 = (const float*)d_in[2];
    const float* y2 = (const float*)d_in[3];
    const float* wq1 = (const float*)d_in[4];
    const float* bq1 = (const float*)d_in[5];
    const float* wq2 = (const float*)d_in[6];
    const float* bq2 = (const float*)d_in[7];
    const float* wk1 = (const float*)d_in[8];
    const float* bk1 = (const float*)d_in[9];
    const float* wk2 = (const float*)d_in[10];
    const float* bk2 = (const float*)d_in[11];
    const float* wv1 = (const float*)d_in[12];
    const float* bv1 = (const float*)d_in[13];
    const float* wv2 = (const float*)d_in[14];
    const float* bv2 = (const float*)d_in[15];
    const float* scale = (const float*)d_in[16];

    char* ws = (char*)d_ws;
    u16* y1b  = (u16*)(ws + 0);
    u16* y2b  = (u16*)(ws + 2097152);
    u16* wk1b = (u16*)(ws + 4194304);
    u16* wk2b = (u16*)(ws + 4456448);
    u16* wv1b = (u16*)(ws + 4718592);
    u16* wv2b = (u16*)(ws + 5242880);
    u16* wq1t = (u16*)(ws + 5767168);
    u16* wq2t = (u16*)(ws + 5898240);
    u16* k1b  = (u16*)(ws + 6029312);
    u16* k2b  = (u16*)(ws + 7077888);
    u16* kk11 = (u16*)(ws + 8126464);
    u16* kk12 = (u16*)(ws + 10223616);
    u16* kk21 = (u16*)(ws + 12320768);
    u16* kk22 = (u16*)(ws + 14417920);
    u16* vt1  = (u16*)(ws + 16515072);
    u16* vt2  = (u16*)(ws + 18612224);
    float* eb1 = (float*)(ws + 20709376);
    float* eb2 = (float*)(ws + 20717568);

    float* out1 = (float*)d_out;
    float* out2 = out1 + (size_t)B_ * C_ * N_;

    hipLaunchKernelGGL(conv_all, dim3(11264), dim3(256), 0, stream,
                       y1, y2, wk1, wk2, wv1, wv2, y1b, y2b, wk1b, wk2b, wv1b, wv2b);
    hipLaunchKernelGGL(conv_wqt, dim3(512), dim3(256), 0, stream, wq1, wq2, wq1t, wq2t);
    hipLaunchKernelGGL(gemm_gk, dim3(2, 4, 32), dim3(64), 0, stream,
                       y1b, y2b, wk1b, wk2b, bk1, bk2, k1b, k2b);
    hipLaunchKernelGGL(ebias_k, dim3(16), dim3(256), 0, stream, k1b, k2b, bq1, bq2, eb1, eb2);
    hipLaunchKernelGGL(gemm_gkk, dim3(2, 8, 64), dim3(64), 0, stream,
                       k1b, k2b, wq1t, wq2t, kk11, kk12, kk21, kk22);
    hipLaunchKernelGGL(gemm_gv, dim3(8, 2, 32), dim3(64), 0, stream,
                       wv1b, wv2b, y1b, y2b, bv1, bv2, vt1, vt2);
    hipLaunchKernelGGL(main_attn, dim3(1024), dim3(256), 0, stream,
                       x1, x2, kk11, kk12, kk21, kk22, vt1, vt2, eb1, eb2, scale,
                       out1, out2);
}